// Round 4
// baseline (1975.093 us; speedup 1.0000x reference)
//
#include <hip/hip_runtime.h>
#include <hip/hip_bf16.h>

typedef __hip_bfloat16 bf16;

#define BB 8
#define QQ 900
#define DD 256
#define NH 8
#define HD 32
#define NPTS 4
#define FFD 1024
#define HH 100
#define WW2 100
#define HWTOT 10000

__device__ inline float tofloat(float x) { return x; }
__device__ inline float tofloat(bf16 x) { return __bfloat162float(x); }
__device__ inline void storev(bf16* p, float v) { *p = __float2bfloat16(v); }
__device__ inline void storev(float* p, float v) { *p = v; }

// ---------------- GEMM: C[M,N] = act(A[M,K] @ W[N,K]^T + bias), bf16 out ----------
// 64x64 tile, BK=16, 256 threads, 4x4 per thread, fp32 accumulate.
template <typename TA, int ACT>
__global__ void gemm_kernel(const TA* __restrict__ A, const float* __restrict__ W,
                            const float* __restrict__ bias, bf16* __restrict__ C,
                            int M, int N, int K) {
    __shared__ float As[16][65];
    __shared__ float Bs[16][65];
    const int bm = blockIdx.y * 64, bn = blockIdx.x * 64;
    const int tid = threadIdx.x;
    const int tx = tid & 15, ty = tid >> 4;
    float acc[4][4] = {};
    for (int k0 = 0; k0 < K; k0 += 16) {
#pragma unroll
        for (int i = 0; i < 4; ++i) {
            int e = tid + i * 256;
            int r = e >> 4, kk = e & 15;
            int row = bm + r;
            As[kk][r] = (row < M) ? tofloat(A[(size_t)row * K + k0 + kk]) : 0.f;
        }
#pragma unroll
        for (int i = 0; i < 4; ++i) {
            int e = tid + i * 256;
            int r = e >> 4, kk = e & 15;
            int col = bn + r;
            Bs[kk][r] = (col < N) ? W[(size_t)col * K + k0 + kk] : 0.f;
        }
        __syncthreads();
#pragma unroll
        for (int kk = 0; kk < 16; ++kk) {
            float a[4], b[4];
#pragma unroll
            for (int i = 0; i < 4; ++i) a[i] = As[kk][ty * 4 + i];
#pragma unroll
            for (int j = 0; j < 4; ++j) b[j] = Bs[kk][tx * 4 + j];
#pragma unroll
            for (int i = 0; i < 4; ++i)
#pragma unroll
                for (int j = 0; j < 4; ++j) acc[i][j] += a[i] * b[j];
        }
        __syncthreads();
    }
#pragma unroll
    for (int i = 0; i < 4; ++i) {
        int row = bm + ty * 4 + i;
        if (row >= M) continue;
#pragma unroll
        for (int j = 0; j < 4; ++j) {
            int col = bn + tx * 4 + j;
            if (col >= N) continue;
            float v = acc[i][j] + bias[col];
            if (ACT == 1) v = fmaxf(v, 0.f);
            storev(&C[(size_t)row * N + col], v);
        }
    }
}

// ---------------- MHA: one block per (b,h,q); qkv is bf16 workspace ----------------
__global__ void mha_kernel(const bf16* __restrict__ qkv, bf16* __restrict__ o) {
    const int q = blockIdx.x, h = blockIdx.y, b = blockIdx.z;
    const int tid = threadIdx.x;
    __shared__ float qv[HD];
    __shared__ float sc[QQ];
    __shared__ float red[256];
    const size_t base = (size_t)b * QQ * 768;
    if (tid < HD) qv[tid] = tofloat(qkv[base + (size_t)q * 768 + h * HD + tid]);
    __syncthreads();
    const float scale = 0.17677669529663687f;  // 1/sqrt(32)
    for (int k = tid; k < QQ; k += 256) {
        const bf16* kr = &qkv[base + (size_t)k * 768 + DD + h * HD];
        float s = 0.f;
#pragma unroll
        for (int c = 0; c < HD; ++c) s += qv[c] * tofloat(kr[c]);
        sc[k] = s * scale;
    }
    __syncthreads();
    float m = -1e30f;
    for (int k = tid; k < QQ; k += 256) m = fmaxf(m, sc[k]);
    red[tid] = m;
    __syncthreads();
    for (int s = 128; s > 0; s >>= 1) {
        if (tid < s) red[tid] = fmaxf(red[tid], red[tid + s]);
        __syncthreads();
    }
    m = red[0];
    __syncthreads();
    float sum = 0.f;
    for (int k = tid; k < QQ; k += 256) {
        float e = __expf(sc[k] - m);
        sc[k] = e;
        sum += e;
    }
    red[tid] = sum;
    __syncthreads();
    for (int s = 128; s > 0; s >>= 1) {
        if (tid < s) red[tid] += red[tid + s];
        __syncthreads();
    }
    const float inv = 1.f / red[0];
    __syncthreads();  // red reused below
    const int c = tid & 31, sl = tid >> 5;
    float acc = 0.f;
    for (int k = sl; k < QQ; k += 8) {
        acc += sc[k] * tofloat(qkv[base + (size_t)k * 768 + 2 * DD + h * HD + c]);
    }
    red[tid] = acc;
    __syncthreads();
    if (tid < HD) {
        float a = 0.f;
#pragma unroll
        for (int s2 = 0; s2 < 8; ++s2) a += red[s2 * 32 + tid];
        storev(&o[((size_t)b * QQ + q) * DD + h * HD + tid], a * inv);
    }
}

// ---------------- residual + LayerNorm: one block (256 thr) per row ----------------
template <typename TR, typename TO>
__global__ void add_ln_kernel(const TR* __restrict__ resid, const bf16* __restrict__ y,
                              const float* __restrict__ g, const float* __restrict__ bta,
                              TO* __restrict__ out) {
    const int row = blockIdx.x;
    const int tid = threadIdx.x;
    __shared__ float red[256];
    const size_t idx = (size_t)row * DD + tid;
    float v = tofloat(resid[idx]) + tofloat(y[idx]);
    red[tid] = v;
    __syncthreads();
    for (int s = 128; s > 0; s >>= 1) {
        if (tid < s) red[tid] += red[tid + s];
        __syncthreads();
    }
    const float mean = red[0] * (1.f / DD);
    __syncthreads();
    const float d = v - mean;
    red[tid] = d * d;
    __syncthreads();
    for (int s = 128; s > 0; s >>= 1) {
        if (tid < s) red[tid] += red[tid + s];
        __syncthreads();
    }
    const float rstd = rsqrtf(red[0] * (1.f / DD) + 1e-5f);
    storev(&out[idx], d * rstd * g[tid] + bta[tid]);
}

// ---------------- fused deformable attention (vproj folded in): one block per (b,q) ----
// out[b,q,ch] = g[h]·Wv[ch,:]^T + wsum[h]*bv[ch],  h = ch>>5, where
// g[h][:] = sum_{p,corner} w * mem[pos][:],  wsum[h] = sum of valid blend weights.
__global__ void deform_kernel(const bf16* __restrict__ t, const float* __restrict__ mem,
                              const float* __restrict__ vproj_w, const float* __restrict__ vproj_b,
                              const float* __restrict__ offs_w, const float* __restrict__ offs_b,
                              const float* __restrict__ attw_w, const float* __restrict__ attw_b,
                              const float* __restrict__ ref_w, const float* __restrict__ ref_b,
                              bf16* __restrict__ samp) {
    const int q = blockIdx.x, b = blockIdx.y;
    const int tid = threadIdx.x;
    __shared__ float trow[DD];
    __shared__ float dots[98];
    __shared__ float aw[32];
    __shared__ int sidx[32][4];
    __shared__ float swt[32][4];
    __shared__ float wsum[NH];
    __shared__ float gbuf[NH][DD];
    trow[tid] = tofloat(t[((size_t)b * QQ + q) * DD + tid]);
    __syncthreads();
    if (tid < 98) {
        const float* wrow;
        float bb;
        if (tid < 64) {
            wrow = offs_w + tid * DD;
            bb = offs_b[tid];
        } else if (tid < 96) {
            wrow = attw_w + (tid - 64) * DD;
            bb = attw_b[tid - 64];
        } else {
            wrow = ref_w + (tid - 96) * DD;
            bb = ref_b[tid - 96];
        }
        float s = bb;
        for (int c = 0; c < DD; ++c) s += trow[c] * wrow[c];
        dots[tid] = s;
    }
    __syncthreads();
    if (tid < NH) {  // softmax over 4 points for head `tid`
        float mx = -1e30f;
#pragma unroll
        for (int p = 0; p < NPTS; ++p) mx = fmaxf(mx, dots[64 + tid * NPTS + p]);
        float e[NPTS], sm = 0.f;
#pragma unroll
        for (int p = 0; p < NPTS; ++p) {
            e[p] = __expf(dots[64 + tid * NPTS + p] - mx);
            sm += e[p];
        }
#pragma unroll
        for (int p = 0; p < NPTS; ++p) aw[tid * NPTS + p] = e[p] / sm;
    }
    __syncthreads();
    if (tid < 32) {  // per (h,p) = tid: corner indices + blend weights
        const float refx = 1.f / (1.f + __expf(-dots[96]));
        const float refy = 1.f / (1.f + __expf(-dots[97]));
        const float ox = dots[tid * 2 + 0];
        const float oy = dots[tid * 2 + 1];
        const float x = (refx + ox * (1.f / WW2)) * WW2 - 0.5f;
        const float y = (refy + oy * (1.f / HH)) * HH - 0.5f;
        const float x0f = floorf(x), y0f = floorf(y);
        const float lx = x - x0f, ly = y - y0f;
        const int x0 = (int)x0f, y0 = (int)y0f;
        const float a = aw[tid];
        const float cw[4] = {(1 - lx) * (1 - ly), lx * (1 - ly), (1 - lx) * ly, lx * ly};
        const int cx[4] = {x0, x0 + 1, x0, x0 + 1};
        const int cy[4] = {y0, y0, y0 + 1, y0 + 1};
#pragma unroll
        for (int cc = 0; cc < 4; ++cc) {
            const bool valid = cx[cc] >= 0 && cx[cc] < WW2 && cy[cc] >= 0 && cy[cc] < HH;
            const int xi = min(max(cx[cc], 0), WW2 - 1);
            const int yi = min(max(cy[cc], 0), HH - 1);
            sidx[tid][cc] = yi * WW2 + xi;
            swt[tid][cc] = valid ? a * cw[cc] : 0.f;
        }
    }
    __syncthreads();
    if (tid < NH) {
        float s = 0.f;
#pragma unroll
        for (int p = 0; p < NPTS; ++p)
#pragma unroll
            for (int cc = 0; cc < 4; ++cc) s += swt[tid * NPTS + p][cc];
        wsum[tid] = s;
    }
    __syncthreads();
    // blended memory rows per head (channel = tid)
    const float* mb = mem + (size_t)b * HWTOT * DD;
#pragma unroll
    for (int h = 0; h < NH; ++h) {
        float acc = 0.f;
#pragma unroll
        for (int p = 0; p < NPTS; ++p) {
            const int hp = h * NPTS + p;
#pragma unroll
            for (int cc = 0; cc < 4; ++cc) {
                acc += swt[hp][cc] * mb[(size_t)sidx[hp][cc] * DD + tid];
            }
        }
        gbuf[h][tid] = acc;
    }
    __syncthreads();
    // projection: out channel = tid, head h = tid>>5
    const int h = tid >> 5;
    const float* wr = vproj_w + (size_t)tid * DD;
    float s = wsum[h] * vproj_b[tid];
    for (int k = 0; k < DD; k += 4) {
        const float4 w4 = *(const float4*)(wr + k);
        s += gbuf[h][k] * w4.x + gbuf[h][k + 1] * w4.y + gbuf[h][k + 2] * w4.z +
             gbuf[h][k + 3] * w4.w;
    }
    storev(&samp[((size_t)b * QQ + q) * DD + tid], s);
}

extern "C" void kernel_launch(void* const* d_in, const int* in_sizes, int n_in,
                              void* d_out, int out_size, void* d_ws, size_t ws_size,
                              hipStream_t stream) {
    const float* tgt = (const float*)d_in[0];
    const float* memory = (const float*)d_in[1];
    // d_in[2]=H, d_in[3]=W (int scalars, hardcoded: 100x100)
    const float* in_proj_w = (const float*)d_in[4];
    const float* in_proj_b = (const float*)d_in[5];
    const float* out_proj_w = (const float*)d_in[6];
    const float* out_proj_b = (const float*)d_in[7];
    const float* norm1_s = (const float*)d_in[8];
    const float* norm1_b = (const float*)d_in[9];
    const float* norm2_s = (const float*)d_in[10];
    const float* norm2_b = (const float*)d_in[11];
    const float* norm3_s = (const float*)d_in[12];
    const float* norm3_b = (const float*)d_in[13];
    const float* vproj_w = (const float*)d_in[14];
    const float* vproj_b = (const float*)d_in[15];
    const float* offs_w = (const float*)d_in[16];
    const float* offs_b = (const float*)d_in[17];
    const float* attw_w = (const float*)d_in[18];
    const float* attw_b = (const float*)d_in[19];
    const float* ref_w = (const float*)d_in[20];
    const float* ref_b = (const float*)d_in[21];
    const float* cout_w = (const float*)d_in[22];
    const float* cout_b = (const float*)d_in[23];
    const float* ffn_w1 = (const float*)d_in[24];
    const float* ffn_b1 = (const float*)d_in[25];
    const float* ffn_w2 = (const float*)d_in[26];
    const float* ffn_b2 = (const float*)d_in[27];

    const int M = BB * QQ;  // 7200
    // workspace (bf16 intermediates): 18,432,000 elems = 36.9 MB
    bf16* ws = (bf16*)d_ws;
    bf16* qkv = ws;                    // 7200*768
    bf16* o = qkv + (size_t)M * 768;   // 7200*256
    bf16* t1 = o + (size_t)M * DD;     // 7200*256
    bf16* tmp = t1 + (size_t)M * DD;   // 7200*256
    bf16* ffh = tmp + (size_t)M * DD;  // 7200*1024
    bf16* samp = o;                    // alias: o dead after out_proj
    bf16* t2n = qkv;                   // alias: qkv dead after mha

    // 1. QKV projection (A = fp32 input)
    gemm_kernel<float, 0><<<dim3(768 / 64, (M + 63) / 64), 256, 0, stream>>>(
        tgt, in_proj_w, in_proj_b, qkv, M, 768, DD);
    // 2. self-attention
    mha_kernel<<<dim3(QQ, NH, BB), 256, 0, stream>>>(qkv, o);
    // 3. out projection
    gemm_kernel<bf16, 0><<<dim3(DD / 64, (M + 63) / 64), 256, 0, stream>>>(
        o, out_proj_w, out_proj_b, tmp, M, DD, DD);
    // 4. LN1 (residual = tgt fp32) -> t1 bf16
    add_ln_kernel<float, bf16><<<M, 256, 0, stream>>>(tgt, tmp, norm1_s, norm1_b, t1);
    // 5. fused deformable sampling + value projection
    deform_kernel<<<dim3(QQ, BB), 256, 0, stream>>>(t1, memory, vproj_w, vproj_b, offs_w,
                                                    offs_b, attw_w, attw_b, ref_w, ref_b, samp);
    // 6. cross-attn out projection
    gemm_kernel<bf16, 0><<<dim3(DD / 64, (M + 63) / 64), 256, 0, stream>>>(
        samp, cout_w, cout_b, tmp, M, DD, DD);
    // 7. LN2 -> t2n bf16
    add_ln_kernel<bf16, bf16><<<M, 256, 0, stream>>>(t1, tmp, norm2_s, norm2_b, t2n);
    // 8. FFN layer 1 (+ReLU)
    gemm_kernel<bf16, 1><<<dim3(FFD / 64, (M + 63) / 64), 256, 0, stream>>>(
        t2n, ffn_w1, ffn_b1, ffh, M, FFD, DD);
    // 9. FFN layer 2
    gemm_kernel<bf16, 0><<<dim3(DD / 64, (M + 63) / 64), 256, 0, stream>>>(
        ffh, ffn_w2, ffn_b2, tmp, M, DD, FFD);
    // 10. LN3 -> fp32 output
    add_ln_kernel<bf16, float><<<M, 256, 0, stream>>>(t2n, tmp, norm3_s, norm3_b,
                                                      (float*)d_out);
}

// Round 5
// 1159.527 us; speedup vs baseline: 1.7034x; 1.7034x over previous
//
#include <hip/hip_runtime.h>
#include <hip/hip_bf16.h>

typedef __hip_bfloat16 bf16;

#define BB 8
#define QQ 900
#define DD 256
#define NH 8
#define HD 32
#define NPTS 4
#define FFD 1024
#define HH 100
#define WW2 100
#define HWTOT 10000

#define QT 64
#define KTC 128
#define NCHUNK ((QQ + KTC - 1) / KTC)  // 8

__device__ inline float tofloat(float x) { return x; }
__device__ inline float tofloat(bf16 x) { return __bfloat162float(x); }
__device__ inline float bf2f(unsigned short u) {
    return __uint_as_float(((unsigned int)u) << 16);
}
__device__ inline void storev(bf16* p, float v) { *p = __float2bfloat16(v); }
__device__ inline void storev(float* p, float v) { *p = v; }

// ---------------- GEMM: C[M,N] = act(A[M,K] @ W[N,K]^T + bias), bf16 out ----------
// 64x64 tile, BK=16, 256 threads, 4x4 per thread, fp32 accumulate.
template <typename TA, int ACT>
__global__ void gemm_kernel(const TA* __restrict__ A, const float* __restrict__ W,
                            const float* __restrict__ bias, bf16* __restrict__ C,
                            int M, int N, int K) {
    __shared__ float As[16][65];
    __shared__ float Bs[16][65];
    const int bm = blockIdx.y * 64, bn = blockIdx.x * 64;
    const int tid = threadIdx.x;
    const int tx = tid & 15, ty = tid >> 4;
    float acc[4][4] = {};
    for (int k0 = 0; k0 < K; k0 += 16) {
#pragma unroll
        for (int i = 0; i < 4; ++i) {
            int e = tid + i * 256;
            int r = e >> 4, kk = e & 15;
            int row = bm + r;
            As[kk][r] = (row < M) ? tofloat(A[(size_t)row * K + k0 + kk]) : 0.f;
        }
#pragma unroll
        for (int i = 0; i < 4; ++i) {
            int e = tid + i * 256;
            int r = e >> 4, kk = e & 15;
            int col = bn + r;
            Bs[kk][r] = (col < N) ? W[(size_t)col * K + k0 + kk] : 0.f;
        }
        __syncthreads();
#pragma unroll
        for (int kk = 0; kk < 16; ++kk) {
            float a[4], b[4];
#pragma unroll
            for (int i = 0; i < 4; ++i) a[i] = As[kk][ty * 4 + i];
#pragma unroll
            for (int j = 0; j < 4; ++j) b[j] = Bs[kk][tx * 4 + j];
#pragma unroll
            for (int i = 0; i < 4; ++i)
#pragma unroll
                for (int j = 0; j < 4; ++j) acc[i][j] += a[i] * b[j];
        }
        __syncthreads();
    }
#pragma unroll
    for (int i = 0; i < 4; ++i) {
        int row = bm + ty * 4 + i;
        if (row >= M) continue;
#pragma unroll
        for (int j = 0; j < 4; ++j) {
            int col = bn + tx * 4 + j;
            if (col >= N) continue;
            float v = acc[i][j] + bias[col];
            if (ACT == 1) v = fmaxf(v, 0.f);
            storev(&C[(size_t)row * N + col], v);
        }
    }
}

// ---------------- tiled flash-style MHA ----------------
// grid (15, NH, BB), 256 threads. Block = 64-query tile of one (b,h).
// 4 threads per query row (sub = tid&3); K/V streamed through LDS in 128-key
// chunks; online softmax; O accumulated in registers, cross-sub shfl reduce.
__global__ __launch_bounds__(256) void mha_tiled_kernel(const bf16* __restrict__ qkv,
                                                        bf16* __restrict__ o) {
    const int qt = blockIdx.x, h = blockIdx.y, b = blockIdx.z;
    const int tid = threadIdx.x;
    const int row = tid >> 2, sub = tid & 3;
    __shared__ float Qs[QT][36];   // pad 36: 16B-aligned rows, <=2-way banks
    __shared__ float Ks[KTC][36];
    __shared__ float Vs[KTC][36];
    const size_t base = (size_t)b * QQ * 768;
    const int q0 = qt * QT;

    // ---- load Q tile (row, channels sub*8..sub*8+8) ----
    {
        const int qg = q0 + row;
        float qv[8];
        if (qg < QQ) {
            const uint4 u = *(const uint4*)(qkv + base + (size_t)qg * 768 + h * HD + sub * 8);
            const unsigned short* s = (const unsigned short*)&u;
#pragma unroll
            for (int j = 0; j < 8; ++j) qv[j] = bf2f(s[j]);
        } else {
#pragma unroll
            for (int j = 0; j < 8; ++j) qv[j] = 0.f;
        }
#pragma unroll
        for (int j = 0; j < 8; ++j) Qs[row][sub * 8 + j] = qv[j];
    }

    float Opart[HD];
#pragma unroll
    for (int c = 0; c < HD; ++c) Opart[c] = 0.f;
    float m_run = -1e30f, l_run = 0.f;
    const float scale = 0.17677669529663687f;  // 1/sqrt(32)

    const int kr = tid >> 1, coff = (tid & 1) * 16;  // K/V loader mapping

    for (int ch = 0; ch < NCHUNK; ++ch) {
        const int k0 = ch * KTC;
        __syncthreads();  // previous chunk's LDS reads done (also covers Q store)
        {
            const int kg = k0 + kr;
            float kv[16], vv[16];
            if (kg < QQ) {
                const bf16* pk = qkv + base + (size_t)kg * 768 + DD + h * HD + coff;
                const bf16* pv = qkv + base + (size_t)kg * 768 + 2 * DD + h * HD + coff;
                const uint4 u0 = *(const uint4*)pk;
                const uint4 u1 = *(const uint4*)(pk + 8);
                const uint4 w0 = *(const uint4*)pv;
                const uint4 w1 = *(const uint4*)(pv + 8);
                const unsigned short* a0 = (const unsigned short*)&u0;
                const unsigned short* a1 = (const unsigned short*)&u1;
                const unsigned short* b0 = (const unsigned short*)&w0;
                const unsigned short* b1 = (const unsigned short*)&w1;
#pragma unroll
                for (int j = 0; j < 8; ++j) {
                    kv[j] = bf2f(a0[j]);
                    kv[8 + j] = bf2f(a1[j]);
                    vv[j] = bf2f(b0[j]);
                    vv[8 + j] = bf2f(b1[j]);
                }
            } else {
#pragma unroll
                for (int j = 0; j < 16; ++j) {
                    kv[j] = 0.f;
                    vv[j] = 0.f;
                }
            }
#pragma unroll
            for (int j = 0; j < 16; ++j) {
                Ks[kr][coff + j] = kv[j];
                Vs[kr][coff + j] = vv[j];
            }
        }
        __syncthreads();

        // ---- scores for this thread's 32 columns (j = jj*4 + sub) ----
        float p[32];
        float mx = -1e30f;
#pragma unroll
        for (int jj = 0; jj < 32; ++jj) {
            const int j = jj * 4 + sub;
            const float4* kp = (const float4*)&Ks[j][0];
            const float4* qp = (const float4*)&Qs[row][0];
            float s = 0.f;
#pragma unroll
            for (int c4 = 0; c4 < 8; ++c4) {
                const float4 kq = kp[c4];
                const float4 qq = qp[c4];
                s += qq.x * kq.x + qq.y * kq.y + qq.z * kq.z + qq.w * kq.w;
            }
            s *= scale;
            if (k0 + j >= QQ) s = -1e30f;
            p[jj] = s;
            mx = fmaxf(mx, s);
        }
        mx = fmaxf(mx, __shfl_xor(mx, 1));
        mx = fmaxf(mx, __shfl_xor(mx, 2));
        const float m_new = fmaxf(m_run, mx);
        const float alpha = __expf(m_run - m_new);
        float ps = 0.f;
#pragma unroll
        for (int jj = 0; jj < 32; ++jj) {
            p[jj] = __expf(p[jj] - m_new);
            ps += p[jj];
        }
        ps += __shfl_xor(ps, 1);
        ps += __shfl_xor(ps, 2);
        l_run = l_run * alpha + ps;
        m_run = m_new;
#pragma unroll
        for (int c = 0; c < HD; ++c) Opart[c] *= alpha;
#pragma unroll
        for (int jj = 0; jj < 32; ++jj) {
            const int j = jj * 4 + sub;
            const float pj = p[jj];
            const float4* vp = (const float4*)&Vs[j][0];
#pragma unroll
            for (int c4 = 0; c4 < 8; ++c4) {
                const float4 vq = vp[c4];
                Opart[c4 * 4 + 0] += pj * vq.x;
                Opart[c4 * 4 + 1] += pj * vq.y;
                Opart[c4 * 4 + 2] += pj * vq.z;
                Opart[c4 * 4 + 3] += pj * vq.w;
            }
        }
    }

    // ---- cross-sub reduce + write ----
#pragma unroll
    for (int c = 0; c < HD; ++c) {
        Opart[c] += __shfl_xor(Opart[c], 1);
        Opart[c] += __shfl_xor(Opart[c], 2);
    }
    const int qg = q0 + row;
    if (qg < QQ) {
        const float inv = 1.f / l_run;
#pragma unroll
        for (int j = 0; j < 8; ++j) {
            storev(&o[((size_t)b * QQ + qg) * DD + h * HD + sub * 8 + j],
                   Opart[sub * 8 + j] * inv);
        }
    }
}

// ---------------- residual + LayerNorm: one block (256 thr) per row ----------------
template <typename TR, typename TO>
__global__ void add_ln_kernel(const TR* __restrict__ resid, const bf16* __restrict__ y,
                              const float* __restrict__ g, const float* __restrict__ bta,
                              TO* __restrict__ out) {
    const int row = blockIdx.x;
    const int tid = threadIdx.x;
    __shared__ float red[256];
    const size_t idx = (size_t)row * DD + tid;
    float v = tofloat(resid[idx]) + tofloat(y[idx]);
    red[tid] = v;
    __syncthreads();
    for (int s = 128; s > 0; s >>= 1) {
        if (tid < s) red[tid] += red[tid + s];
        __syncthreads();
    }
    const float mean = red[0] * (1.f / DD);
    __syncthreads();
    const float d = v - mean;
    red[tid] = d * d;
    __syncthreads();
    for (int s = 128; s > 0; s >>= 1) {
        if (tid < s) red[tid] += red[tid + s];
        __syncthreads();
    }
    const float rstd = rsqrtf(red[0] * (1.f / DD) + 1e-5f);
    storev(&out[idx], d * rstd * g[tid] + bta[tid]);
}

// ---------------- fused deformable attention (vproj folded in): one block per (b,q) ----
__global__ void deform_kernel(const bf16* __restrict__ t, const float* __restrict__ mem,
                              const float* __restrict__ vproj_w, const float* __restrict__ vproj_b,
                              const float* __restrict__ offs_w, const float* __restrict__ offs_b,
                              const float* __restrict__ attw_w, const float* __restrict__ attw_b,
                              const float* __restrict__ ref_w, const float* __restrict__ ref_b,
                              bf16* __restrict__ samp) {
    const int q = blockIdx.x, b = blockIdx.y;
    const int tid = threadIdx.x;
    __shared__ float trow[DD];
    __shared__ float dots[98];
    __shared__ float aw[32];
    __shared__ int sidx[32][4];
    __shared__ float swt[32][4];
    __shared__ float wsum[NH];
    __shared__ float gbuf[NH][DD];
    trow[tid] = tofloat(t[((size_t)b * QQ + q) * DD + tid]);
    __syncthreads();
    if (tid < 98) {
        const float* wrow;
        float bb;
        if (tid < 64) {
            wrow = offs_w + tid * DD;
            bb = offs_b[tid];
        } else if (tid < 96) {
            wrow = attw_w + (tid - 64) * DD;
            bb = attw_b[tid - 64];
        } else {
            wrow = ref_w + (tid - 96) * DD;
            bb = ref_b[tid - 96];
        }
        float s = bb;
        for (int c = 0; c < DD; ++c) s += trow[c] * wrow[c];
        dots[tid] = s;
    }
    __syncthreads();
    if (tid < NH) {
        float mx = -1e30f;
#pragma unroll
        for (int p = 0; p < NPTS; ++p) mx = fmaxf(mx, dots[64 + tid * NPTS + p]);
        float e[NPTS], sm = 0.f;
#pragma unroll
        for (int p = 0; p < NPTS; ++p) {
            e[p] = __expf(dots[64 + tid * NPTS + p] - mx);
            sm += e[p];
        }
#pragma unroll
        for (int p = 0; p < NPTS; ++p) aw[tid * NPTS + p] = e[p] / sm;
    }
    __syncthreads();
    if (tid < 32) {
        const float refx = 1.f / (1.f + __expf(-dots[96]));
        const float refy = 1.f / (1.f + __expf(-dots[97]));
        const float ox = dots[tid * 2 + 0];
        const float oy = dots[tid * 2 + 1];
        const float x = (refx + ox * (1.f / WW2)) * WW2 - 0.5f;
        const float y = (refy + oy * (1.f / HH)) * HH - 0.5f;
        const float x0f = floorf(x), y0f = floorf(y);
        const float lx = x - x0f, ly = y - y0f;
        const int x0 = (int)x0f, y0 = (int)y0f;
        const float a = aw[tid];
        const float cw[4] = {(1 - lx) * (1 - ly), lx * (1 - ly), (1 - lx) * ly, lx * ly};
        const int cx[4] = {x0, x0 + 1, x0, x0 + 1};
        const int cy[4] = {y0, y0, y0 + 1, y0 + 1};
#pragma unroll
        for (int cc = 0; cc < 4; ++cc) {
            const bool valid = cx[cc] >= 0 && cx[cc] < WW2 && cy[cc] >= 0 && cy[cc] < HH;
            const int xi = min(max(cx[cc], 0), WW2 - 1);
            const int yi = min(max(cy[cc], 0), HH - 1);
            sidx[tid][cc] = yi * WW2 + xi;
            swt[tid][cc] = valid ? a * cw[cc] : 0.f;
        }
    }
    __syncthreads();
    if (tid < NH) {
        float s = 0.f;
#pragma unroll
        for (int p = 0; p < NPTS; ++p)
#pragma unroll
            for (int cc = 0; cc < 4; ++cc) s += swt[tid * NPTS + p][cc];
        wsum[tid] = s;
    }
    __syncthreads();
    const float* mb = mem + (size_t)b * HWTOT * DD;
#pragma unroll
    for (int h = 0; h < NH; ++h) {
        float acc = 0.f;
#pragma unroll
        for (int p = 0; p < NPTS; ++p) {
            const int hp = h * NPTS + p;
#pragma unroll
            for (int cc = 0; cc < 4; ++cc) {
                acc += swt[hp][cc] * mb[(size_t)sidx[hp][cc] * DD + tid];
            }
        }
        gbuf[h][tid] = acc;
    }
    __syncthreads();
    const int h = tid >> 5;
    const float* wr = vproj_w + (size_t)tid * DD;
    float s = wsum[h] * vproj_b[tid];
    for (int k = 0; k < DD; k += 4) {
        const float4 w4 = *(const float4*)(wr + k);
        s += gbuf[h][k] * w4.x + gbuf[h][k + 1] * w4.y + gbuf[h][k + 2] * w4.z +
             gbuf[h][k + 3] * w4.w;
    }
    storev(&samp[((size_t)b * QQ + q) * DD + tid], s);
}

extern "C" void kernel_launch(void* const* d_in, const int* in_sizes, int n_in,
                              void* d_out, int out_size, void* d_ws, size_t ws_size,
                              hipStream_t stream) {
    const float* tgt = (const float*)d_in[0];
    const float* memory = (const float*)d_in[1];
    const float* in_proj_w = (const float*)d_in[4];
    const float* in_proj_b = (const float*)d_in[5];
    const float* out_proj_w = (const float*)d_in[6];
    const float* out_proj_b = (const float*)d_in[7];
    const float* norm1_s = (const float*)d_in[8];
    const float* norm1_b = (const float*)d_in[9];
    const float* norm2_s = (const float*)d_in[10];
    const float* norm2_b = (const float*)d_in[11];
    const float* norm3_s = (const float*)d_in[12];
    const float* norm3_b = (const float*)d_in[13];
    const float* vproj_w = (const float*)d_in[14];
    const float* vproj_b = (const float*)d_in[15];
    const float* offs_w = (const float*)d_in[16];
    const float* offs_b = (const float*)d_in[17];
    const float* attw_w = (const float*)d_in[18];
    const float* attw_b = (const float*)d_in[19];
    const float* ref_w = (const float*)d_in[20];
    const float* ref_b = (const float*)d_in[21];
    const float* cout_w = (const float*)d_in[22];
    const float* cout_b = (const float*)d_in[23];
    const float* ffn_w1 = (const float*)d_in[24];
    const float* ffn_b1 = (const float*)d_in[25];
    const float* ffn_w2 = (const float*)d_in[26];
    const float* ffn_b2 = (const float*)d_in[27];

    const int M = BB * QQ;  // 7200
    bf16* ws = (bf16*)d_ws;
    bf16* qkv = ws;                    // 7200*768
    bf16* o = qkv + (size_t)M * 768;   // 7200*256
    bf16* t1 = o + (size_t)M * DD;     // 7200*256
    bf16* tmp = t1 + (size_t)M * DD;   // 7200*256
    bf16* ffh = tmp + (size_t)M * DD;  // 7200*1024
    bf16* samp = o;                    // alias: o dead after out_proj
    bf16* t2n = qkv;                   // alias: qkv dead after mha

    // 1. QKV projection (A = fp32 input)
    gemm_kernel<float, 0><<<dim3(768 / 64, (M + 63) / 64), 256, 0, stream>>>(
        tgt, in_proj_w, in_proj_b, qkv, M, 768, DD);
    // 2. self-attention (tiled flash-style)
    mha_tiled_kernel<<<dim3((QQ + QT - 1) / QT, NH, BB), 256, 0, stream>>>(qkv, o);
    // 3. out projection
    gemm_kernel<bf16, 0><<<dim3(DD / 64, (M + 63) / 64), 256, 0, stream>>>(
        o, out_proj_w, out_proj_b, tmp, M, DD, DD);
    // 4. LN1 (residual = tgt fp32) -> t1 bf16
    add_ln_kernel<float, bf16><<<M, 256, 0, stream>>>(tgt, tmp, norm1_s, norm1_b, t1);
    // 5. fused deformable sampling + value projection
    deform_kernel<<<dim3(QQ, BB), 256, 0, stream>>>(t1, memory, vproj_w, vproj_b, offs_w,
                                                    offs_b, attw_w, attw_b, ref_w, ref_b, samp);
    // 6. cross-attn out projection
    gemm_kernel<bf16, 0><<<dim3(DD / 64, (M + 63) / 64), 256, 0, stream>>>(
        samp, cout_w, cout_b, tmp, M, DD, DD);
    // 7. LN2 -> t2n bf16
    add_ln_kernel<bf16, bf16><<<M, 256, 0, stream>>>(t1, tmp, norm2_s, norm2_b, t2n);
    // 8. FFN layer 1 (+ReLU)
    gemm_kernel<bf16, 1><<<dim3(FFD / 64, (M + 63) / 64), 256, 0, stream>>>(
        t2n, ffn_w1, ffn_b1, ffh, M, FFD, DD);
    // 9. FFN layer 2
    gemm_kernel<bf16, 0><<<dim3(DD / 64, (M + 63) / 64), 256, 0, stream>>>(
        ffh, ffn_w2, ffn_b2, tmp, M, DD, FFD);
    // 10. LN3 -> fp32 output
    add_ln_kernel<bf16, float><<<M, 256, 0, stream>>>(t2n, tmp, norm3_s, norm3_b,
                                                      (float*)d_out);
}

// Round 6
// 555.575 us; speedup vs baseline: 3.5550x; 2.0871x over previous
//
#include <hip/hip_runtime.h>
#include <hip/hip_bf16.h>

typedef __hip_bfloat16 bf16;
typedef __attribute__((ext_vector_type(8))) short short8;
typedef __attribute__((ext_vector_type(4))) float f32x4;

#define BB 8
#define QQ 900
#define DD 256
#define NH 8
#define HD 32
#define NPTS 4
#define FFD 1024
#define HH 100
#define WW2 100
#define HWTOT 10000

#define QT 64
#define KTC 128
#define NCHUNK ((QQ + KTC - 1) / KTC)  // 8
#define QB 4                            // queries per deform block

__device__ inline float tofloat(float x) { return x; }
__device__ inline float tofloat(bf16 x) { return __bfloat162float(x); }
__device__ inline float bf2f(unsigned short u) {
    return __uint_as_float(((unsigned int)u) << 16);
}
__device__ inline void storev(bf16* p, float v) { *p = __float2bfloat16(v); }
__device__ inline void storev(float* p, float v) { *p = v; }

// ---------------- pack kernel: fp32 weights/activations -> bf16 workspace ----------
// wpk layout (bf16 units): [0) in_proj_w 196608 | out_proj_w 65536 | cout_w 65536 |
//   ffn_w1 262144 | ffn_w2 262144 | vproj_w 65536 | dw 32768 ] then tgtb 1843200,
//   then dbias (fp32, 128).
__global__ void pack_kernel(const float* __restrict__ in_proj_w, const float* __restrict__ out_proj_w,
                            const float* __restrict__ cout_w, const float* __restrict__ ffn_w1,
                            const float* __restrict__ ffn_w2, const float* __restrict__ vproj_w,
                            const float* __restrict__ offs_w, const float* __restrict__ attw_w,
                            const float* __restrict__ ref_w, const float* __restrict__ offs_b,
                            const float* __restrict__ attw_b, const float* __restrict__ ref_b,
                            const float* __restrict__ tgt, bf16* __restrict__ wpk,
                            bf16* __restrict__ tgtb, float* __restrict__ dbias) {
    const int idx = blockIdx.x * 256 + threadIdx.x;
    const int TOT = 950272 + 1843200 + 128;
    if (idx >= TOT) return;
    if (idx < 196608) {
        wpk[idx] = __float2bfloat16(in_proj_w[idx]);
    } else if (idx < 262144) {
        wpk[idx] = __float2bfloat16(out_proj_w[idx - 196608]);
    } else if (idx < 327680) {
        wpk[idx] = __float2bfloat16(cout_w[idx - 262144]);
    } else if (idx < 589824) {
        wpk[idx] = __float2bfloat16(ffn_w1[idx - 327680]);
    } else if (idx < 851968) {
        wpk[idx] = __float2bfloat16(ffn_w2[idx - 589824]);
    } else if (idx < 917504) {
        wpk[idx] = __float2bfloat16(vproj_w[idx - 851968]);
    } else if (idx < 950272) {
        const int j = idx - 917504;
        const int r = j >> 8, c = j & 255;
        float v = 0.f;
        if (r < 64) v = offs_w[r * 256 + c];
        else if (r < 96) v = attw_w[(r - 64) * 256 + c];
        else if (r < 98) v = ref_w[(r - 96) * 256 + c];
        wpk[idx] = __float2bfloat16(v);
    } else if (idx < 950272 + 1843200) {
        const int j = idx - 950272;
        tgtb[j] = __float2bfloat16(tgt[j]);
    } else {
        const int j = idx - (950272 + 1843200);
        float v = 0.f;
        if (j < 64) v = offs_b[j];
        else if (j < 96) v = attw_b[j - 64];
        else if (j < 98) v = ref_b[j - 96];
        dbias[j] = v;
    }
}

// ---------------- MFMA GEMM: C[M,N] = act(A[M,K] @ W[N,K]^T + bias) ----------------
// A, W bf16; C = OT (bf16 or fp32); fp32 accumulate via mfma_f32_16x16x32_bf16.
// 64x64 tile, BK=32, 256 thr = 4 waves; wave w owns rows [w*16,w*16+16) x 64 cols.
// Frags: a[j]=A[m=lane&15][k=(lane>>4)*8+j]; b[j]=W[n=lane&15][k=(lane>>4)*8+j];
// D: col=lane&15, row=(lane>>4)*4+reg (m89-verified).
template <int ACT, typename OT>
__global__ __launch_bounds__(256) void gemm_mfma_kernel(const bf16* __restrict__ A,
                                                        const bf16* __restrict__ W,
                                                        const float* __restrict__ bias,
                                                        OT* __restrict__ C, int M, int N, int K) {
    __shared__ unsigned short As[64][56];  // stride 56: 16B-aligned rows, 2-way banks
    __shared__ unsigned short Bs[64][56];
    const int bm = blockIdx.y * 64, bn = blockIdx.x * 64;
    const int tid = threadIdx.x;
    const int lane = tid & 63, wave = tid >> 6;
    const int sr = tid >> 2, sc = (tid & 3) * 8;  // staging: row, k-chunk
    f32x4 acc[4] = {{0.f, 0.f, 0.f, 0.f}, {0.f, 0.f, 0.f, 0.f},
                    {0.f, 0.f, 0.f, 0.f}, {0.f, 0.f, 0.f, 0.f}};
    const uint4 zero4 = {0u, 0u, 0u, 0u};
    for (int k0 = 0; k0 < K; k0 += 32) {
        __syncthreads();
        {
            const int arow = bm + sr;
            uint4 a4 = (arow < M) ? *(const uint4*)(A + (size_t)arow * K + k0 + sc) : zero4;
            *(uint4*)&As[sr][sc] = a4;
            const int wrow = bn + sr;
            uint4 b4 = (wrow < N) ? *(const uint4*)(W + (size_t)wrow * K + k0 + sc) : zero4;
            *(uint4*)&Bs[sr][sc] = b4;
        }
        __syncthreads();
        const short8 af = *(const short8*)&As[wave * 16 + (lane & 15)][(lane >> 4) * 8];
#pragma unroll
        for (int ct = 0; ct < 4; ++ct) {
            const short8 bf = *(const short8*)&Bs[ct * 16 + (lane & 15)][(lane >> 4) * 8];
            acc[ct] = __builtin_amdgcn_mfma_f32_16x16x32_bf16(af, bf, acc[ct], 0, 0, 0);
        }
    }
#pragma unroll
    for (int ct = 0; ct < 4; ++ct) {
        const int col = bn + ct * 16 + (lane & 15);
        const float bv = bias[col];
#pragma unroll
        for (int r = 0; r < 4; ++r) {
            const int row = bm + wave * 16 + (lane >> 4) * 4 + r;
            if (row < M) {
                float v = acc[ct][r] + bv;
                if (ACT == 1) v = fmaxf(v, 0.f);
                storev(&C[(size_t)row * N + col], v);
            }
        }
    }
}

// ---------------- tiled flash-style MHA (unchanged from round 5) ----------------
__global__ __launch_bounds__(256) void mha_tiled_kernel(const bf16* __restrict__ qkv,
                                                        bf16* __restrict__ o) {
    const int qt = blockIdx.x, h = blockIdx.y, b = blockIdx.z;
    const int tid = threadIdx.x;
    const int row = tid >> 2, sub = tid & 3;
    __shared__ float Qs[QT][36];
    __shared__ float Ks[KTC][36];
    __shared__ float Vs[KTC][36];
    const size_t base = (size_t)b * QQ * 768;
    const int q0 = qt * QT;
    {
        const int qg = q0 + row;
        float qv[8];
        if (qg < QQ) {
            const uint4 u = *(const uint4*)(qkv + base + (size_t)qg * 768 + h * HD + sub * 8);
            const unsigned short* s = (const unsigned short*)&u;
#pragma unroll
            for (int j = 0; j < 8; ++j) qv[j] = bf2f(s[j]);
        } else {
#pragma unroll
            for (int j = 0; j < 8; ++j) qv[j] = 0.f;
        }
#pragma unroll
        for (int j = 0; j < 8; ++j) Qs[row][sub * 8 + j] = qv[j];
    }
    float Opart[HD];
#pragma unroll
    for (int c = 0; c < HD; ++c) Opart[c] = 0.f;
    float m_run = -1e30f, l_run = 0.f;
    const float scale = 0.17677669529663687f;
    const int kr = tid >> 1, coff = (tid & 1) * 16;
    for (int ch = 0; ch < NCHUNK; ++ch) {
        const int k0 = ch * KTC;
        __syncthreads();
        {
            const int kg = k0 + kr;
            float kv[16], vv[16];
            if (kg < QQ) {
                const bf16* pk = qkv + base + (size_t)kg * 768 + DD + h * HD + coff;
                const bf16* pv = qkv + base + (size_t)kg * 768 + 2 * DD + h * HD + coff;
                const uint4 u0 = *(const uint4*)pk;
                const uint4 u1 = *(const uint4*)(pk + 8);
                const uint4 w0 = *(const uint4*)pv;
                const uint4 w1 = *(const uint4*)(pv + 8);
                const unsigned short* a0 = (const unsigned short*)&u0;
                const unsigned short* a1 = (const unsigned short*)&u1;
                const unsigned short* b0 = (const unsigned short*)&w0;
                const unsigned short* b1 = (const unsigned short*)&w1;
#pragma unroll
                for (int j = 0; j < 8; ++j) {
                    kv[j] = bf2f(a0[j]);
                    kv[8 + j] = bf2f(a1[j]);
                    vv[j] = bf2f(b0[j]);
                    vv[8 + j] = bf2f(b1[j]);
                }
            } else {
#pragma unroll
                for (int j = 0; j < 16; ++j) {
                    kv[j] = 0.f;
                    vv[j] = 0.f;
                }
            }
#pragma unroll
            for (int j = 0; j < 16; ++j) {
                Ks[kr][coff + j] = kv[j];
                Vs[kr][coff + j] = vv[j];
            }
        }
        __syncthreads();
        float p[32];
        float mx = -1e30f;
#pragma unroll
        for (int jj = 0; jj < 32; ++jj) {
            const int j = jj * 4 + sub;
            const float4* kp = (const float4*)&Ks[j][0];
            const float4* qp = (const float4*)&Qs[row][0];
            float s = 0.f;
#pragma unroll
            for (int c4 = 0; c4 < 8; ++c4) {
                const float4 kq = kp[c4];
                const float4 qq = qp[c4];
                s += qq.x * kq.x + qq.y * kq.y + qq.z * kq.z + qq.w * kq.w;
            }
            s *= scale;
            if (k0 + j >= QQ) s = -1e30f;
            p[jj] = s;
            mx = fmaxf(mx, s);
        }
        mx = fmaxf(mx, __shfl_xor(mx, 1));
        mx = fmaxf(mx, __shfl_xor(mx, 2));
        const float m_new = fmaxf(m_run, mx);
        const float alpha = __expf(m_run - m_new);
        float ps = 0.f;
#pragma unroll
        for (int jj = 0; jj < 32; ++jj) {
            p[jj] = __expf(p[jj] - m_new);
            ps += p[jj];
        }
        ps += __shfl_xor(ps, 1);
        ps += __shfl_xor(ps, 2);
        l_run = l_run * alpha + ps;
        m_run = m_new;
#pragma unroll
        for (int c = 0; c < HD; ++c) Opart[c] *= alpha;
#pragma unroll
        for (int jj = 0; jj < 32; ++jj) {
            const int j = jj * 4 + sub;
            const float pj = p[jj];
            const float4* vp = (const float4*)&Vs[j][0];
#pragma unroll
            for (int c4 = 0; c4 < 8; ++c4) {
                const float4 vq = vp[c4];
                Opart[c4 * 4 + 0] += pj * vq.x;
                Opart[c4 * 4 + 1] += pj * vq.y;
                Opart[c4 * 4 + 2] += pj * vq.z;
                Opart[c4 * 4 + 3] += pj * vq.w;
            }
        }
    }
#pragma unroll
    for (int c = 0; c < HD; ++c) {
        Opart[c] += __shfl_xor(Opart[c], 1);
        Opart[c] += __shfl_xor(Opart[c], 2);
    }
    const int qg = q0 + row;
    if (qg < QQ) {
        const float inv = 1.f / l_run;
#pragma unroll
        for (int j = 0; j < 8; ++j) {
            storev(&o[((size_t)b * QQ + qg) * DD + h * HD + sub * 8 + j],
                   Opart[sub * 8 + j] * inv);
        }
    }
}

// ---------------- residual + LayerNorm ----------------
template <typename TR, typename TO>
__global__ void add_ln_kernel(const TR* __restrict__ resid, const bf16* __restrict__ y,
                              const float* __restrict__ g, const float* __restrict__ bta,
                              TO* __restrict__ out) {
    const int row = blockIdx.x;
    const int tid = threadIdx.x;
    __shared__ float red[256];
    const size_t idx = (size_t)row * DD + tid;
    float v = tofloat(resid[idx]) + tofloat(y[idx]);
    red[tid] = v;
    __syncthreads();
    for (int s = 128; s > 0; s >>= 1) {
        if (tid < s) red[tid] += red[tid + s];
        __syncthreads();
    }
    const float mean = red[0] * (1.f / DD);
    __syncthreads();
    const float d = v - mean;
    red[tid] = d * d;
    __syncthreads();
    for (int s = 128; s > 0; s >>= 1) {
        if (tid < s) red[tid] += red[tid + s];
        __syncthreads();
    }
    const float rstd = rsqrtf(red[0] * (1.f / DD) + 1e-5f);
    storev(&out[idx], d * rstd * g[tid] + bta[tid]);
}

// ---------------- deformable sampling + fused vproj, QB=4 queries/block ----------
// dots[M,128] precomputed by GEMM (offs 0..63, attw 64..95, ref 96..97).
__global__ __launch_bounds__(256) void deform_kernel(
    const float* __restrict__ dots, const float* __restrict__ mem,
    const bf16* __restrict__ vwpk, const float* __restrict__ vproj_b,
    bf16* __restrict__ samp) {
    const int qt = blockIdx.x, b = blockIdx.y;
    const int tid = threadIdx.x;
    const int q0 = qt * QB;
    __shared__ int sidx[QB][32][4];
    __shared__ float swt[QB][32][4];
    __shared__ float wsum[QB][NH];
    __shared__ float G[QB * NH * DD];  // 32 KB

    // ---- phase 1: locations/weights (threads 0..127; 2 full waves) ----
    if (tid < 128) {
        const int q = tid >> 5, hp = tid & 31;
        const float* dr = dots + ((size_t)b * QQ + q0 + q) * 128;
        const float ox = dr[hp * 2], oy = dr[hp * 2 + 1];
        float ad = dr[64 + hp];
        const float rx = dr[96], ry = dr[97];
        // softmax over the 4 points of this head (lanes hp*... grouped by 4)
        float mx = ad;
        mx = fmaxf(mx, __shfl_xor(mx, 1));
        mx = fmaxf(mx, __shfl_xor(mx, 2));
        float e = __expf(ad - mx);
        float sm = e;
        sm += __shfl_xor(sm, 1);
        sm += __shfl_xor(sm, 2);
        const float a = e / sm;
        const float refx = 1.f / (1.f + __expf(-rx));
        const float refy = 1.f / (1.f + __expf(-ry));
        const float x = (refx + ox * (1.f / WW2)) * WW2 - 0.5f;
        const float y = (refy + oy * (1.f / HH)) * HH - 0.5f;
        const float x0f = floorf(x), y0f = floorf(y);
        const float lx = x - x0f, ly = y - y0f;
        const int x0 = (int)x0f, y0 = (int)y0f;
        const float cw[4] = {(1 - lx) * (1 - ly), lx * (1 - ly), (1 - lx) * ly, lx * ly};
        const int cx[4] = {x0, x0 + 1, x0, x0 + 1};
        const int cy[4] = {y0, y0, y0 + 1, y0 + 1};
        float cs = 0.f;
#pragma unroll
        for (int cc = 0; cc < 4; ++cc) {
            const bool valid = cx[cc] >= 0 && cx[cc] < WW2 && cy[cc] >= 0 && cy[cc] < HH;
            const int xi = min(max(cx[cc], 0), WW2 - 1);
            const int yi = min(max(cy[cc], 0), HH - 1);
            sidx[q][hp][cc] = yi * WW2 + xi;
            const float w = valid ? a * cw[cc] : 0.f;
            swt[q][hp][cc] = w;
            cs += w;
        }
        cs += __shfl_xor(cs, 1);
        cs += __shfl_xor(cs, 2);
        if ((hp & 3) == 0) wsum[q][hp >> 2] = cs;
    }
    __syncthreads();

    // ---- phase 2: float4 gather into G[q][h][256] ----
    {
        const int q = tid >> 6, c4o = (tid & 63) * 4;
        const float* mb = mem + (size_t)b * HWTOT * DD;
        float4* Gp = (float4*)G;
#pragma unroll
        for (int h = 0; h < NH; ++h) {
            float4 acc = {0.f, 0.f, 0.f, 0.f};
#pragma unroll
            for (int p = 0; p < NPTS; ++p) {
                const int hp = h * NPTS + p;
#pragma unroll
                for (int cc = 0; cc < 4; ++cc) {
                    const float w = swt[q][hp][cc];
                    const float4 v = *(const float4*)(mb + (size_t)sidx[q][hp][cc] * DD + c4o);
                    acc.x += w * v.x;
                    acc.y += w * v.y;
                    acc.z += w * v.z;
                    acc.w += w * v.w;
                }
            }
            Gp[(q * NH + h) * 64 + (tid & 63)] = acc;
        }
    }
    __syncthreads();

    // ---- phase 3: vproj, weight row reused across QB queries ----
    {
        const int ch = tid, h = ch >> 5;
        const bf16* wr = vwpk + (size_t)ch * DD;
        const float bv = vproj_b[ch];
        float acc[QB];
#pragma unroll
        for (int q = 0; q < QB; ++q) acc[q] = wsum[q][h] * bv;
        for (int k = 0; k < DD; k += 8) {
            const uint4 u = *(const uint4*)(wr + k);
            const unsigned short* us = (const unsigned short*)&u;
            float wf[8];
#pragma unroll
            for (int j = 0; j < 8; ++j) wf[j] = bf2f(us[j]);
#pragma unroll
            for (int q = 0; q < QB; ++q) {
                const float* gq = &G[(q * NH + h) * DD + k];
#pragma unroll
                for (int j = 0; j < 8; ++j) acc[q] += gq[j] * wf[j];
            }
        }
#pragma unroll
        for (int q = 0; q < QB; ++q) {
            storev(&samp[((size_t)b * QQ + q0 + q) * DD + ch], acc[q]);
        }
    }
}

extern "C" void kernel_launch(void* const* d_in, const int* in_sizes, int n_in,
                              void* d_out, int out_size, void* d_ws, size_t ws_size,
                              hipStream_t stream) {
    const float* tgt = (const float*)d_in[0];
    const float* memory = (const float*)d_in[1];
    const float* in_proj_w = (const float*)d_in[4];
    const float* in_proj_b = (const float*)d_in[5];
    const float* out_proj_w = (const float*)d_in[6];
    const float* out_proj_b = (const float*)d_in[7];
    const float* norm1_s = (const float*)d_in[8];
    const float* norm1_b = (const float*)d_in[9];
    const float* norm2_s = (const float*)d_in[10];
    const float* norm2_b = (const float*)d_in[11];
    const float* norm3_s = (const float*)d_in[12];
    const float* norm3_b = (const float*)d_in[13];
    const float* vproj_b = (const float*)d_in[15];
    const float* offs_w = (const float*)d_in[16];
    const float* offs_b = (const float*)d_in[17];
    const float* attw_w = (const float*)d_in[18];
    const float* attw_b = (const float*)d_in[19];
    const float* ref_w = (const float*)d_in[20];
    const float* ref_b = (const float*)d_in[21];
    const float* cout_b = (const float*)d_in[23];
    const float* ffn_b1 = (const float*)d_in[25];
    const float* ffn_b2 = (const float*)d_in[27];
    const float* vproj_w = (const float*)d_in[14];
    const float* cout_w = (const float*)d_in[22];
    const float* ffn_w1 = (const float*)d_in[24];
    const float* ffn_w2 = (const float*)d_in[26];

    const int M = BB * QQ;  // 7200
    bf16* ws = (bf16*)d_ws;
    size_t off = 0;
    bf16* qkv = ws + off;  off += (size_t)M * 768;   // 5,529,600
    bf16* o = ws + off;    off += (size_t)M * DD;    // 1,843,200
    bf16* t1 = ws + off;   off += (size_t)M * DD;
    bf16* tmp = ws + off;  off += (size_t)M * DD;
    bf16* ffh = ws + off;  off += (size_t)M * FFD;   // 7,372,800
    bf16* tgtb = ws + off; off += (size_t)M * DD;
    bf16* wpk = ws + off;  off += 950272;
    float* dbias = (float*)(ws + off);  // 128 floats (256 bf16 units)
    bf16* samp = o;                     // alias: o dead after out_proj
    bf16* t2n = qkv;                    // alias: qkv dead after mha
    float* dots = (float*)ffh;          // alias: ffh used only after deform

    bf16* w_in = wpk;
    bf16* w_out = wpk + 196608;
    bf16* w_cout = wpk + 262144;
    bf16* w_ffn1 = wpk + 327680;
    bf16* w_ffn2 = wpk + 589824;
    bf16* w_vproj = wpk + 851968;
    bf16* w_dots = wpk + 917504;

    const int MT = (M + 63) / 64;  // 113

    // 0. pack weights + tgt to bf16, build dots weight/bias
    pack_kernel<<<(950272 + 1843200 + 128 + 255) / 256, 256, 0, stream>>>(
        in_proj_w, out_proj_w, cout_w, ffn_w1, ffn_w2, vproj_w, offs_w, attw_w, ref_w,
        offs_b, attw_b, ref_b, tgt, wpk, tgtb, dbias);
    // 1. QKV projection
    gemm_mfma_kernel<0, bf16><<<dim3(12, MT), 256, 0, stream>>>(tgtb, w_in, in_proj_b, qkv,
                                                                M, 768, DD);
    // 2. self-attention
    mha_tiled_kernel<<<dim3((QQ + QT - 1) / QT, NH, BB), 256, 0, stream>>>(qkv, o);
    // 3. out projection
    gemm_mfma_kernel<0, bf16><<<dim3(4, MT), 256, 0, stream>>>(o, w_out, out_proj_b, tmp,
                                                               M, DD, DD);
    // 4. LN1
    add_ln_kernel<float, bf16><<<M, 256, 0, stream>>>(tgt, tmp, norm1_s, norm1_b, t1);
    // 5a. deform param dots GEMM -> fp32 [M,128]
    gemm_mfma_kernel<0, float><<<dim3(2, MT), 256, 0, stream>>>(t1, w_dots, dbias, dots,
                                                                M, 128, DD);
    // 5b. sampling + fused vproj
    deform_kernel<<<dim3(QQ / QB, BB), 256, 0, stream>>>(dots, memory, w_vproj, vproj_b, samp);
    // 6. cross-attn out projection
    gemm_mfma_kernel<0, bf16><<<dim3(4, MT), 256, 0, stream>>>(samp, w_cout, cout_b, tmp,
                                                               M, DD, DD);
    // 7. LN2
    add_ln_kernel<bf16, bf16><<<M, 256, 0, stream>>>(t1, tmp, norm2_s, norm2_b, t2n);
    // 8. FFN layer 1 (+ReLU)
    gemm_mfma_kernel<1, bf16><<<dim3(16, MT), 256, 0, stream>>>(t2n, w_ffn1, ffn_b1, ffh,
                                                                M, FFD, DD);
    // 9. FFN layer 2
    gemm_mfma_kernel<0, bf16><<<dim3(4, MT), 256, 0, stream>>>(ffh, w_ffn2, ffn_b2, tmp,
                                                               M, DD, FFD);
    // 10. LN3 -> fp32 output
    add_ln_kernel<bf16, float><<<M, 256, 0, stream>>>(t2n, tmp, norm3_s, norm3_b,
                                                      (float*)d_out);
}

// Round 7
// 385.226 us; speedup vs baseline: 5.1271x; 1.4422x over previous
//
#include <hip/hip_runtime.h>
#include <hip/hip_bf16.h>

typedef __hip_bfloat16 bf16;
typedef __attribute__((ext_vector_type(8))) short short8;
typedef __attribute__((ext_vector_type(4))) float f32x4;

#define BB 8
#define QQ 900
#define DD 256
#define NH 8
#define HD 32
#define NPTS 4
#define FFD 1024
#define HH 100
#define WW2 100
#define HWTOT 10000

#define QT 64
#define KTC 128
#define NCHUNK ((QQ + KTC - 1) / KTC)  // 8
#define QB 4                            // queries per deform block

__device__ inline float tofloat(float x) { return x; }
__device__ inline float tofloat(bf16 x) { return __bfloat162float(x); }
__device__ inline float bf2f(unsigned short u) {
    return __uint_as_float(((unsigned int)u) << 16);
}
__device__ inline void storev(bf16* p, float v) { *p = __float2bfloat16(v); }
__device__ inline void storev(float* p, float v) { *p = v; }

// ---------------- pack kernel: fp32 weights/activations -> bf16 workspace ----------
__global__ void pack_kernel(const float* __restrict__ in_proj_w, const float* __restrict__ out_proj_w,
                            const float* __restrict__ cout_w, const float* __restrict__ ffn_w1,
                            const float* __restrict__ ffn_w2, const float* __restrict__ vproj_w,
                            const float* __restrict__ offs_w, const float* __restrict__ attw_w,
                            const float* __restrict__ ref_w, const float* __restrict__ offs_b,
                            const float* __restrict__ attw_b, const float* __restrict__ ref_b,
                            const float* __restrict__ tgt, bf16* __restrict__ wpk,
                            bf16* __restrict__ tgtb, float* __restrict__ dbias) {
    const int idx = blockIdx.x * 256 + threadIdx.x;
    const int TOT = 950272 + 1843200 + 128;
    if (idx >= TOT) return;
    if (idx < 196608) {
        wpk[idx] = __float2bfloat16(in_proj_w[idx]);
    } else if (idx < 262144) {
        wpk[idx] = __float2bfloat16(out_proj_w[idx - 196608]);
    } else if (idx < 327680) {
        wpk[idx] = __float2bfloat16(cout_w[idx - 262144]);
    } else if (idx < 589824) {
        wpk[idx] = __float2bfloat16(ffn_w1[idx - 327680]);
    } else if (idx < 851968) {
        wpk[idx] = __float2bfloat16(ffn_w2[idx - 589824]);
    } else if (idx < 917504) {
        wpk[idx] = __float2bfloat16(vproj_w[idx - 851968]);
    } else if (idx < 950272) {
        const int j = idx - 917504;
        const int r = j >> 8, c = j & 255;
        float v = 0.f;
        if (r < 64) v = offs_w[r * 256 + c];
        else if (r < 96) v = attw_w[(r - 64) * 256 + c];
        else if (r < 98) v = ref_w[(r - 96) * 256 + c];
        wpk[idx] = __float2bfloat16(v);
    } else if (idx < 950272 + 1843200) {
        const int j = idx - 950272;
        tgtb[j] = __float2bfloat16(tgt[j]);
    } else {
        const int j = idx - (950272 + 1843200);
        float v = 0.f;
        if (j < 64) v = offs_b[j];
        else if (j < 96) v = attw_b[j - 64];
        else if (j < 98) v = ref_b[j - 96];
        dbias[j] = v;
    }
}

// ---------------- MFMA GEMM: C[M,N] = act(A[M,K] @ W[N,K]^T + bias) ----------------
template <int ACT, typename OT>
__global__ __launch_bounds__(256) void gemm_mfma_kernel(const bf16* __restrict__ A,
                                                        const bf16* __restrict__ W,
                                                        const float* __restrict__ bias,
                                                        OT* __restrict__ C, int M, int N, int K) {
    __shared__ unsigned short As[64][56];
    __shared__ unsigned short Bs[64][56];
    const int bm = blockIdx.y * 64, bn = blockIdx.x * 64;
    const int tid = threadIdx.x;
    const int lane = tid & 63, wave = tid >> 6;
    const int sr = tid >> 2, sc = (tid & 3) * 8;
    f32x4 acc[4] = {{0.f, 0.f, 0.f, 0.f}, {0.f, 0.f, 0.f, 0.f},
                    {0.f, 0.f, 0.f, 0.f}, {0.f, 0.f, 0.f, 0.f}};
    const uint4 zero4 = {0u, 0u, 0u, 0u};
    for (int k0 = 0; k0 < K; k0 += 32) {
        __syncthreads();
        {
            const int arow = bm + sr;
            uint4 a4 = (arow < M) ? *(const uint4*)(A + (size_t)arow * K + k0 + sc) : zero4;
            *(uint4*)&As[sr][sc] = a4;
            const int wrow = bn + sr;
            uint4 b4 = (wrow < N) ? *(const uint4*)(W + (size_t)wrow * K + k0 + sc) : zero4;
            *(uint4*)&Bs[sr][sc] = b4;
        }
        __syncthreads();
        const short8 af = *(const short8*)&As[wave * 16 + (lane & 15)][(lane >> 4) * 8];
#pragma unroll
        for (int ct = 0; ct < 4; ++ct) {
            const short8 bf = *(const short8*)&Bs[ct * 16 + (lane & 15)][(lane >> 4) * 8];
            acc[ct] = __builtin_amdgcn_mfma_f32_16x16x32_bf16(af, bf, acc[ct], 0, 0, 0);
        }
    }
#pragma unroll
    for (int ct = 0; ct < 4; ++ct) {
        const int col = bn + ct * 16 + (lane & 15);
        const float bv = bias[col];
#pragma unroll
        for (int r = 0; r < 4; ++r) {
            const int row = bm + wave * 16 + (lane >> 4) * 4 + r;
            if (row < M) {
                float v = acc[ct][r] + bv;
                if (ACT == 1) v = fmaxf(v, 0.f);
                storev(&C[(size_t)row * N + col], v);
            }
        }
    }
}

// ---------------- MFMA flash MHA ----------------
// grid (15, NH, BB), 256 thr = 4 waves; wave owns 16 Q-rows of a 64-row tile.
// S = Q·K^T via mfma (K=HD=32, one step); online softmax on C-layout;
// P -> bf16 -> per-wave LDS -> A-frags; V staged transposed -> B-frags; O += P·V.
__global__ __launch_bounds__(256) void mha_mfma_kernel(const bf16* __restrict__ qkv,
                                                       bf16* __restrict__ o) {
    const int qt = blockIdx.x, h = blockIdx.y, b = blockIdx.z;
    const int tid = threadIdx.x;
    const int lane = tid & 63, wave = tid >> 6;
    const int l15 = lane & 15, g = lane >> 4;
    __shared__ unsigned short Kls[KTC][40];   // 10240 B, row-major K rows
    __shared__ bf16 Vt[HD][136];              // 8704 B, transposed V
    __shared__ bf16 Pls[4][16][136];          // 17408 B, per-wave P
    const size_t base = (size_t)b * QQ * 768;
    const int q0 = qt * QT;

    short8 qa = {0, 0, 0, 0, 0, 0, 0, 0};
    {
        const int qg = q0 + wave * 16 + l15;
        if (qg < QQ)
            qa = *(const short8*)(qkv + base + (size_t)qg * 768 + h * HD + g * 8);
    }
    f32x4 accO[2] = {{0.f, 0.f, 0.f, 0.f}, {0.f, 0.f, 0.f, 0.f}};
    float m_run[4], l_run[4];
#pragma unroll
    for (int r = 0; r < 4; ++r) {
        m_run[r] = -1e30f;
        l_run[r] = 0.f;
    }
    const float scale = 0.17677669529663687f;  // 1/sqrt(32)
    const uint4 zero4 = {0u, 0u, 0u, 0u};

    for (int c = 0; c < NCHUNK; ++c) {
        const int k0 = c * KTC;
        __syncthreads();
        // ---- stage K rows (two passes of 64 rows, 8 bf16 per thread-pass) ----
        {
            const int part = tid & 3, kr = tid >> 2;
#pragma unroll
            for (int pass = 0; pass < 2; ++pass) {
                const int krr = kr + pass * 64;
                const int kg = k0 + krr;
                uint4 kv = (kg < QQ)
                    ? *(const uint4*)(qkv + base + (size_t)kg * 768 + DD + h * HD + part * 8)
                    : zero4;
                *(uint4*)&Kls[krr][part * 8] = kv;
            }
        }
        // ---- stage V transposed: Vt[ch][krow] ----
        {
            const int kr = tid >> 1, ch0 = (tid & 1) * 16;
            const int kg = k0 + kr;
            uint4 v0 = zero4, v1 = zero4;
            if (kg < QQ) {
                const bf16* pv = qkv + base + (size_t)kg * 768 + 2 * DD + h * HD + ch0;
                v0 = *(const uint4*)pv;
                v1 = *(const uint4*)(pv + 8);
            }
            const unsigned short* u0 = (const unsigned short*)&v0;
            const unsigned short* u1 = (const unsigned short*)&v1;
#pragma unroll
            for (int j = 0; j < 8; ++j) {
                ((unsigned short*)&Vt[ch0 + j][kr])[0] = u0[j];
                ((unsigned short*)&Vt[ch0 + 8 + j][kr])[0] = u1[j];
            }
        }
        __syncthreads();

        // ---- S = Q·K^T (8 MFMAs) ----
        f32x4 s[8];
#pragma unroll
        for (int t = 0; t < 8; ++t) {
            const short8 kb = *(const short8*)&Kls[t * 16 + l15][g * 8];
            const f32x4 z = {0.f, 0.f, 0.f, 0.f};
            s[t] = __builtin_amdgcn_mfma_f32_16x16x32_bf16(qa, kb, z, 0, 0, 0);
        }
        // ---- scale + mask + row max ----
        float mx[4] = {-1e30f, -1e30f, -1e30f, -1e30f};
#pragma unroll
        for (int t = 0; t < 8; ++t) {
            const bool cv = (k0 + t * 16 + l15) < QQ;
#pragma unroll
            for (int r = 0; r < 4; ++r) {
                const float v = cv ? s[t][r] * scale : -1e30f;
                s[t][r] = v;
                mx[r] = fmaxf(mx[r], v);
            }
        }
#pragma unroll
        for (int r = 0; r < 4; ++r) {
            mx[r] = fmaxf(mx[r], __shfl_xor(mx[r], 1));
            mx[r] = fmaxf(mx[r], __shfl_xor(mx[r], 2));
            mx[r] = fmaxf(mx[r], __shfl_xor(mx[r], 4));
            mx[r] = fmaxf(mx[r], __shfl_xor(mx[r], 8));
        }
        float alpha[4], rs[4];
#pragma unroll
        for (int r = 0; r < 4; ++r) {
            const float mn = fmaxf(m_run[r], mx[r]);
            alpha[r] = __expf(m_run[r] - mn);
            m_run[r] = mn;
            rs[r] = 0.f;
        }
        // ---- P = exp(S - m), accumulate row sums, spill bf16 to per-wave LDS ----
#pragma unroll
        for (int t = 0; t < 8; ++t) {
#pragma unroll
            for (int r = 0; r < 4; ++r) {
                const float p = __expf(s[t][r] - m_run[r]);
                rs[r] += p;
                Pls[wave][g * 4 + r][t * 16 + l15] = __float2bfloat16(p);
            }
        }
#pragma unroll
        for (int r = 0; r < 4; ++r) {
            rs[r] += __shfl_xor(rs[r], 1);
            rs[r] += __shfl_xor(rs[r], 2);
            rs[r] += __shfl_xor(rs[r], 4);
            rs[r] += __shfl_xor(rs[r], 8);
            l_run[r] = l_run[r] * alpha[r] + rs[r];
        }
        // ---- rescale O, then O += P·V (8 MFMAs) ----
#pragma unroll
        for (int t2 = 0; t2 < 2; ++t2)
#pragma unroll
            for (int r = 0; r < 4; ++r) accO[t2][r] *= alpha[r];
#pragma unroll
        for (int s4 = 0; s4 < 4; ++s4) {
            const short8 pa = *(const short8*)&Pls[wave][l15][s4 * 32 + g * 8];
#pragma unroll
            for (int t2 = 0; t2 < 2; ++t2) {
                const short8 vb = *(const short8*)&Vt[t2 * 16 + l15][s4 * 32 + g * 8];
                accO[t2] = __builtin_amdgcn_mfma_f32_16x16x32_bf16(pa, vb, accO[t2], 0, 0, 0);
            }
        }
    }
    // ---- epilogue ----
#pragma unroll
    for (int r = 0; r < 4; ++r) {
        const int row = q0 + wave * 16 + g * 4 + r;
        if (row < QQ) {
            const float inv = 1.f / l_run[r];
#pragma unroll
            for (int t2 = 0; t2 < 2; ++t2) {
                storev(&o[((size_t)b * QQ + row) * DD + h * HD + t2 * 16 + l15],
                       accO[t2][r] * inv);
            }
        }
    }
}

// ---------------- residual + LayerNorm ----------------
template <typename TR, typename TO>
__global__ void add_ln_kernel(const TR* __restrict__ resid, const bf16* __restrict__ y,
                              const float* __restrict__ g, const float* __restrict__ bta,
                              TO* __restrict__ out) {
    const int row = blockIdx.x;
    const int tid = threadIdx.x;
    __shared__ float red[256];
    const size_t idx = (size_t)row * DD + tid;
    float v = tofloat(resid[idx]) + tofloat(y[idx]);
    red[tid] = v;
    __syncthreads();
    for (int s = 128; s > 0; s >>= 1) {
        if (tid < s) red[tid] += red[tid + s];
        __syncthreads();
    }
    const float mean = red[0] * (1.f / DD);
    __syncthreads();
    const float d = v - mean;
    red[tid] = d * d;
    __syncthreads();
    for (int s = 128; s > 0; s >>= 1) {
        if (tid < s) red[tid] += red[tid + s];
        __syncthreads();
    }
    const float rstd = rsqrtf(red[0] * (1.f / DD) + 1e-5f);
    storev(&out[idx], d * rstd * g[tid] + bta[tid]);
}

// ---------------- deformable sampling + fused vproj, QB=4 queries/block ----------
__global__ __launch_bounds__(256) void deform_kernel(
    const float* __restrict__ dots, const float* __restrict__ mem,
    const bf16* __restrict__ vwpk, const float* __restrict__ vproj_b,
    bf16* __restrict__ samp) {
    const int qt = blockIdx.x, b = blockIdx.y;
    const int tid = threadIdx.x;
    const int q0 = qt * QB;
    __shared__ int sidx[QB][32][4];
    __shared__ float swt[QB][32][4];
    __shared__ float wsum[QB][NH];
    __shared__ float G[QB * NH * DD];

    if (tid < 128) {
        const int q = tid >> 5, hp = tid & 31;
        const float* dr = dots + ((size_t)b * QQ + q0 + q) * 128;
        const float ox = dr[hp * 2], oy = dr[hp * 2 + 1];
        float ad = dr[64 + hp];
        const float rx = dr[96], ry = dr[97];
        float mx = ad;
        mx = fmaxf(mx, __shfl_xor(mx, 1));
        mx = fmaxf(mx, __shfl_xor(mx, 2));
        float e = __expf(ad - mx);
        float sm = e;
        sm += __shfl_xor(sm, 1);
        sm += __shfl_xor(sm, 2);
        const float a = e / sm;
        const float refx = 1.f / (1.f + __expf(-rx));
        const float refy = 1.f / (1.f + __expf(-ry));
        const float x = (refx + ox * (1.f / WW2)) * WW2 - 0.5f;
        const float y = (refy + oy * (1.f / HH)) * HH - 0.5f;
        const float x0f = floorf(x), y0f = floorf(y);
        const float lx = x - x0f, ly = y - y0f;
        const int x0 = (int)x0f, y0 = (int)y0f;
        const float cw[4] = {(1 - lx) * (1 - ly), lx * (1 - ly), (1 - lx) * ly, lx * ly};
        const int cx[4] = {x0, x0 + 1, x0, x0 + 1};
        const int cy[4] = {y0, y0, y0 + 1, y0 + 1};
        float cs = 0.f;
#pragma unroll
        for (int cc = 0; cc < 4; ++cc) {
            const bool valid = cx[cc] >= 0 && cx[cc] < WW2 && cy[cc] >= 0 && cy[cc] < HH;
            const int xi = min(max(cx[cc], 0), WW2 - 1);
            const int yi = min(max(cy[cc], 0), HH - 1);
            sidx[q][hp][cc] = yi * WW2 + xi;
            const float w = valid ? a * cw[cc] : 0.f;
            swt[q][hp][cc] = w;
            cs += w;
        }
        cs += __shfl_xor(cs, 1);
        cs += __shfl_xor(cs, 2);
        if ((hp & 3) == 0) wsum[q][hp >> 2] = cs;
    }
    __syncthreads();

    {
        const int q = tid >> 6, c4o = (tid & 63) * 4;
        const float* mb = mem + (size_t)b * HWTOT * DD;
        float4* Gp = (float4*)G;
#pragma unroll
        for (int h = 0; h < NH; ++h) {
            float4 acc = {0.f, 0.f, 0.f, 0.f};
#pragma unroll
            for (int p = 0; p < NPTS; ++p) {
                const int hp = h * NPTS + p;
#pragma unroll
                for (int cc = 0; cc < 4; ++cc) {
                    const float w = swt[q][hp][cc];
                    const float4 v = *(const float4*)(mb + (size_t)sidx[q][hp][cc] * DD + c4o);
                    acc.x += w * v.x;
                    acc.y += w * v.y;
                    acc.z += w * v.z;
                    acc.w += w * v.w;
                }
            }
            Gp[(q * NH + h) * 64 + (tid & 63)] = acc;
        }
    }
    __syncthreads();

    {
        const int ch = tid, h = ch >> 5;
        const bf16* wr = vwpk + (size_t)ch * DD;
        const float bv = vproj_b[ch];
        float acc[QB];
#pragma unroll
        for (int q = 0; q < QB; ++q) acc[q] = wsum[q][h] * bv;
        for (int k = 0; k < DD; k += 8) {
            const uint4 u = *(const uint4*)(wr + k);
            const unsigned short* us = (const unsigned short*)&u;
            float wf[8];
#pragma unroll
            for (int j = 0; j < 8; ++j) wf[j] = bf2f(us[j]);
#pragma unroll
            for (int q = 0; q < QB; ++q) {
                const float* gq = &G[(q * NH + h) * DD + k];
#pragma unroll
                for (int j = 0; j < 8; ++j) acc[q] += gq[j] * wf[j];
            }
        }
#pragma unroll
        for (int q = 0; q < QB; ++q) {
            storev(&samp[((size_t)b * QQ + q0 + q) * DD + ch], acc[q]);
        }
    }
}

extern "C" void kernel_launch(void* const* d_in, const int* in_sizes, int n_in,
                              void* d_out, int out_size, void* d_ws, size_t ws_size,
                              hipStream_t stream) {
    const float* tgt = (const float*)d_in[0];
    const float* memory = (const float*)d_in[1];
    const float* in_proj_w = (const float*)d_in[4];
    const float* in_proj_b = (const float*)d_in[5];
    const float* out_proj_w = (const float*)d_in[6];
    const float* out_proj_b = (const float*)d_in[7];
    const float* norm1_s = (const float*)d_in[8];
    const float* norm1_b = (const float*)d_in[9];
    const float* norm2_s = (const float*)d_in[10];
    const float* norm2_b = (const float*)d_in[11];
    const float* norm3_s = (const float*)d_in[12];
    const float* norm3_b = (const float*)d_in[13];
    const float* vproj_w = (const float*)d_in[14];
    const float* vproj_b = (const float*)d_in[15];
    const float* offs_w = (const float*)d_in[16];
    const float* offs_b = (const float*)d_in[17];
    const float* attw_w = (const float*)d_in[18];
    const float* attw_b = (const float*)d_in[19];
    const float* ref_w = (const float*)d_in[20];
    const float* ref_b = (const float*)d_in[21];
    const float* cout_w = (const float*)d_in[22];
    const float* cout_b = (const float*)d_in[23];
    const float* ffn_w1 = (const float*)d_in[24];
    const float* ffn_b1 = (const float*)d_in[25];
    const float* ffn_w2 = (const float*)d_in[26];
    const float* ffn_b2 = (const float*)d_in[27];

    const int M = BB * QQ;  // 7200
    bf16* ws = (bf16*)d_ws;
    size_t off = 0;
    bf16* qkv = ws + off;  off += (size_t)M * 768;
    bf16* o = ws + off;    off += (size_t)M * DD;
    bf16* t1 = ws + off;   off += (size_t)M * DD;
    bf16* tmp = ws + off;  off += (size_t)M * DD;
    bf16* ffh = ws + off;  off += (size_t)M * FFD;
    bf16* tgtb = ws + off; off += (size_t)M * DD;
    bf16* wpk = ws + off;  off += 950272;
    float* dbias = (float*)(ws + off);
    bf16* samp = o;
    bf16* t2n = qkv;
    float* dots = (float*)ffh;

    bf16* w_in = wpk;
    bf16* w_out = wpk + 196608;
    bf16* w_cout = wpk + 262144;
    bf16* w_ffn1 = wpk + 327680;
    bf16* w_ffn2 = wpk + 589824;
    bf16* w_vproj = wpk + 851968;
    bf16* w_dots = wpk + 917504;

    const int MT = (M + 63) / 64;  // 113

    pack_kernel<<<(950272 + 1843200 + 128 + 255) / 256, 256, 0, stream>>>(
        in_proj_w, out_proj_w, cout_w, ffn_w1, ffn_w2, vproj_w, offs_w, attw_w, ref_w,
        offs_b, attw_b, ref_b, tgt, wpk, tgtb, dbias);
    gemm_mfma_kernel<0, bf16><<<dim3(12, MT), 256, 0, stream>>>(tgtb, w_in, in_proj_b, qkv,
                                                                M, 768, DD);
    mha_mfma_kernel<<<dim3((QQ + QT - 1) / QT, NH, BB), 256, 0, stream>>>(qkv, o);
    gemm_mfma_kernel<0, bf16><<<dim3(4, MT), 256, 0, stream>>>(o, w_out, out_proj_b, tmp,
                                                               M, DD, DD);
    add_ln_kernel<float, bf16><<<M, 256, 0, stream>>>(tgt, tmp, norm1_s, norm1_b, t1);
    gemm_mfma_kernel<0, float><<<dim3(2, MT), 256, 0, stream>>>(t1, w_dots, dbias, dots,
                                                                M, 128, DD);
    deform_kernel<<<dim3(QQ / QB, BB), 256, 0, stream>>>(dots, memory, w_vproj, vproj_b, samp);
    gemm_mfma_kernel<0, bf16><<<dim3(4, MT), 256, 0, stream>>>(samp, w_cout, cout_b, tmp,
                                                               M, DD, DD);
    add_ln_kernel<bf16, bf16><<<M, 256, 0, stream>>>(t1, tmp, norm2_s, norm2_b, t2n);
    gemm_mfma_kernel<1, bf16><<<dim3(16, MT), 256, 0, stream>>>(t2n, w_ffn1, ffn_b1, ffh,
                                                                M, FFD, DD);
    gemm_mfma_kernel<0, bf16><<<dim3(4, MT), 256, 0, stream>>>(ffh, w_ffn2, ffn_b2, tmp,
                                                               M, DD, FFD);
    add_ln_kernel<bf16, float><<<M, 256, 0, stream>>>(t2n, tmp, norm3_s, norm3_b,
                                                      (float*)d_out);
}